// Round 12
// baseline (141.684 us; speedup 1.0000x reference)
//
#include <hip/hip_runtime.h>

// ---------------------------------------------------------------------------
// GraphSAGE 3-layer encoder. N=50000, E=640000, ch 32 -> 64 -> 128 -> 64.
// R12: fused layers move to 32-node tiles (782 -> 1564 blocks, ~3 -> ~6
// blocks/CU) to double gather-phase memory parallelism; fused_layer1 drops
// its 16KB weight LDS (reads L2-hot wprep). r3 stored bf16.
// GEMM math: split-bf16 MFMA (hi*hi + hi*lo + lo*hi, fp32 acc).
// ---------------------------------------------------------------------------

typedef short bf8 __attribute__((ext_vector_type(8)));   // 8 bf16 in 4 VGPR
typedef short bf4 __attribute__((ext_vector_type(4)));   // 4 bf16 in 2 VGPR
typedef float f32x4 __attribute__((ext_vector_type(4)));

__device__ inline ushort bf16rn(float f) {               // round-to-nearest-even
    unsigned u = __float_as_uint(f);
    return (ushort)((u + 0x7FFFu + ((u >> 16) & 1u)) >> 16);
}
__device__ inline float bf16tof(ushort h) {
    return __uint_as_float(((unsigned)h) << 16);
}
__device__ inline void split8(const float4 pa, const float4 pb, bf8& hi, bf8& lo) {
    const float v[8] = {pa.x, pa.y, pa.z, pa.w, pb.x, pb.y, pb.z, pb.w};
#pragma unroll
    for (int j = 0; j < 8; ++j) {
        const ushort h = bf16rn(v[j]);
        hi[j] = (short)h;
        lo[j] = (short)bf16rn(v[j] - bf16tof(h));
    }
}

// ---- prep: weight hi/lo fragments + zero cnt + x -> bf16 ------------------
__global__ __launch_bounds__(256) void prep_kernel(
    const float* __restrict__ x,
    const float* __restrict__ w1l, const float* __restrict__ w1r,
    const float* __restrict__ w2l, const float* __restrict__ w2r,
    const float* __restrict__ w3l, const float* __restrict__ w3r,
    ushort* __restrict__ wprep, int* __restrict__ cnt,
    ushort* __restrict__ xh, int nN, int nCntZero)
{
    const int g = blockIdx.x * 256 + threadIdx.x;
    const int n = gridDim.x * 256;
    for (int f = g; f < 9216; f += n) {
        int base, KCs, oc0, d0, wstride;
        const float *wa, *wb;
        if (f < 1024)      { base = 0;    KCs = 2; oc0 = 0;  wa = w1l; wb = w1r; d0 = 32;  wstride = 64;  }
        else if (f < 3072) { base = 1024; KCs = 4; oc0 = 0;  wa = w2l; wb = w2r; d0 = 64;  wstride = 128; }
        else if (f < 5120) { base = 3072; KCs = 4; oc0 = 64; wa = w2l; wb = w2r; d0 = 64;  wstride = 128; }
        else if (f < 7168) { base = 5120; KCs = 4; oc0 = 0;  wa = w3l; wb = w3l; d0 = 128; wstride = 64;  }
        else               { base = 7168; KCs = 4; oc0 = 0;  wa = w3r; wb = w3r; d0 = 128; wstride = 64;  }
        const int local = f - base;
        const int lane = local & 63;
        const int s = (local >> 6) & 1;
        const int kcct = local >> 7;
        const int kc = kcct % KCs;
        const int ct = kcct / KCs;
        const int col = oc0 + ct * 16 + (lane & 15);
        const int k0 = kc * 32 + (lane >> 4) * 8;
        ushort h8[8];
#pragma unroll
        for (int j = 0; j < 8; ++j) {
            const int k = k0 + j;
            const float* wr = (k < d0) ? (wa + (size_t)k * wstride)
                                       : (wb + (size_t)(k - d0) * wstride);
            const float v = wr[col];
            const ushort h = bf16rn(v);
            h8[j] = (s == 0) ? h : bf16rn(v - bf16tof(h));
        }
        *reinterpret_cast<int4*>(wprep + (size_t)f * 8) = *reinterpret_cast<const int4*>(h8);
    }
    for (int i = g; i < nCntZero / 4; i += n)
        reinterpret_cast<int4*>(cnt)[i] = make_int4(0, 0, 0, 0);
    const int nxv = nN * 4;                       // 8-element groups of x
    for (int i = g; i < nxv; i += n) {
        const float4 a = reinterpret_cast<const float4*>(x)[i * 2 + 0];
        const float4 b = reinterpret_cast<const float4*>(x)[i * 2 + 1];
        const float v[8] = {a.x, a.y, a.z, a.w, b.x, b.y, b.z, b.w};
        bf8 h;
#pragma unroll
        for (int j = 0; j < 8; ++j) h[j] = (short)bf16rn(v[j]);
        reinterpret_cast<bf8*>(xh)[i] = h;
    }
}

// ---- count: degree + per-edge slot (ushort) -------------------------------
__global__ __launch_bounds__(256) void count_kernel(const int* __restrict__ dst,
                                                    int* __restrict__ cnt,
                                                    ushort* __restrict__ pos, int nE) {
    int i = blockIdx.x * blockDim.x + threadIdx.x;
    int e0 = i * 4;
    if (e0 + 3 < nE) {
        int4 d = *reinterpret_cast<const int4*>(dst + e0);
        ushort4 p;
        p.x = (ushort)atomicAdd(&cnt[d.x], 1);
        p.y = (ushort)atomicAdd(&cnt[d.y], 1);
        p.z = (ushort)atomicAdd(&cnt[d.z], 1);
        p.w = (ushort)atomicAdd(&cnt[d.w], 1);
        *reinterpret_cast<ushort4*>(pos + e0) = p;
    } else {
        for (int e = e0; e < nE; ++e) pos[e] = (ushort)atomicAdd(&cnt[dst[e]], 1);
    }
}

__global__ __launch_bounds__(256) void scan_blocks(const int* __restrict__ cnt,
                                                   int* __restrict__ rowptr,
                                                   int* __restrict__ partials, int nN) {
    __shared__ int wsum[4];
    const int t = threadIdx.x;
    const int lane = t & 63, wid = t >> 6;
    const int base = blockIdx.x * 1024 + t * 4;

    int4 v = make_int4(0, 0, 0, 0);
    if (base + 3 < nN) {
        v = *reinterpret_cast<const int4*>(cnt + base);
    } else {
        if (base + 0 < nN) v.x = cnt[base + 0];
        if (base + 1 < nN) v.y = cnt[base + 1];
        if (base + 2 < nN) v.z = cnt[base + 2];
        if (base + 3 < nN) v.w = cnt[base + 3];
    }
    const int s = v.x + v.y + v.z + v.w;

    int inc = s;
#pragma unroll
    for (int d = 1; d < 64; d <<= 1) {
        int u = __shfl_up(inc, d);
        if (lane >= d) inc += u;
    }
    if (lane == 63) wsum[wid] = inc;
    __syncthreads();
    int woff = 0;
#pragma unroll
    for (int w = 0; w < 4; ++w) woff += (w < wid) ? wsum[w] : 0;

    const int excl = woff + inc - s;
    int4 o;
    o.x = excl; o.y = excl + v.x; o.z = excl + v.x + v.y; o.w = excl + v.x + v.y + v.z;
    if (base + 3 < nN) {
        *reinterpret_cast<int4*>(rowptr + base) = o;
    } else {
        if (base + 0 < nN) rowptr[base + 0] = o.x;
        if (base + 1 < nN) rowptr[base + 1] = o.y;
        if (base + 2 < nN) rowptr[base + 2] = o.z;
        if (base + 3 < nN) rowptr[base + 3] = o.w;
    }
    if (t == 255) partials[blockIdx.x] = woff + inc;
}

__global__ __launch_bounds__(256) void scan_add(int* __restrict__ rowptr,
                                                const int* __restrict__ partials,
                                                int nN, int nE) {
    __shared__ int soff;
    const int t = threadIdx.x;
    if (t < 64) {
        int v = (t < blockIdx.x) ? partials[t] : 0;   // grid <= 64 blocks
#pragma unroll
        for (int d = 32; d >= 1; d >>= 1) v += __shfl_xor(v, d);
        if (t == 0) soff = v;
    }
    __syncthreads();
    const int off = soff;
    const int base = blockIdx.x * 1024 + t * 4;
    if (base + 3 < nN) {
        int4 v = *reinterpret_cast<int4*>(rowptr + base);
        v.x += off; v.y += off; v.z += off; v.w += off;
        *reinterpret_cast<int4*>(rowptr + base) = v;
    } else {
        if (base + 0 < nN) rowptr[base + 0] += off;
        if (base + 1 < nN) rowptr[base + 1] += off;
        if (base + 2 < nN) rowptr[base + 2] += off;
        if (base + 3 < nN) rowptr[base + 3] += off;
    }
    if (blockIdx.x == 0 && t == 0) rowptr[nN] = nE;
}

// ---- fill: pure permutation write (no atomics), ushort csr ----------------
__global__ __launch_bounds__(256) void fill_kernel(const int* __restrict__ src,
                                                   const int* __restrict__ dst,
                                                   const ushort* __restrict__ pos,
                                                   const int* __restrict__ rowptr,
                                                   ushort* __restrict__ csr_src, int nE) {
    int i = blockIdx.x * blockDim.x + threadIdx.x;
    int e0 = i * 4;
    if (e0 + 3 < nE) {
        int4 s4 = *reinterpret_cast<const int4*>(src + e0);
        int4 d4 = *reinterpret_cast<const int4*>(dst + e0);
        ushort4 p4 = *reinterpret_cast<const ushort4*>(pos + e0);
        csr_src[rowptr[d4.x] + p4.x] = (ushort)s4.x;
        csr_src[rowptr[d4.y] + p4.y] = (ushort)s4.y;
        csr_src[rowptr[d4.z] + p4.z] = (ushort)s4.z;
        csr_src[rowptr[d4.w] + p4.w] = (ushort)s4.w;
    } else {
        for (int e = e0; e < nE; ++e)
            csr_src[rowptr[dst[e]] + pos[e]] = (ushort)src[e];
    }
}

// ---- layer 1 fused (32-node tile): h1(hi/lo) = relu([mean(xh)|x]@W1 + b1) -
__global__ __launch_bounds__(256) void fused_layer1(
    const float* __restrict__ x, const ushort* __restrict__ xh,
    const int* __restrict__ rowptr, const ushort* __restrict__ csr_src,
    const ushort* __restrict__ wfrag, const float* __restrict__ b1,
    ushort* __restrict__ h1h, ushort* __restrict__ h1l, int nN)
{
    __shared__ float tile[32 * 36];          // 4608 B

    const int tid = threadIdx.x;
    const int node0 = blockIdx.x * 32;

    {   // gather mean(xh): 32 nodes x 8 lanes x 4ch (8B loads)
        const int nl = tid >> 3;
        const int c = tid & 7;
        const int node = node0 + nl;
        float acc[4] = {0.f, 0.f, 0.f, 0.f};
        if (node < nN) {
            const int beg = rowptr[node], end = rowptr[node + 1];
            int e = beg;
            for (; e + 7 < end; e += 8) {
                int si[8];
#pragma unroll
                for (int j = 0; j < 8; ++j) si[j] = csr_src[e + j];
                bf4 v[8];
#pragma unroll
                for (int j = 0; j < 8; ++j)
                    v[j] = *reinterpret_cast<const bf4*>(xh + (size_t)si[j] * 32 + c * 4);
#pragma unroll
                for (int k = 0; k < 4; ++k)
#pragma unroll
                    for (int j = 0; j < 8; ++j) acc[k] += bf16tof((ushort)v[j][k]);
            }
            for (; e < end; ++e) {
                bf4 v = *reinterpret_cast<const bf4*>(xh + (size_t)csr_src[e] * 32 + c * 4);
#pragma unroll
                for (int k = 0; k < 4; ++k) acc[k] += bf16tof((ushort)v[k]);
            }
            const float sc = 1.0f / (float)max(end - beg, 1);
#pragma unroll
            for (int k = 0; k < 4; ++k) acc[k] *= sc;
        }
        *reinterpret_cast<float4*>(&tile[nl * 36 + c * 4]) =
            make_float4(acc[0], acc[1], acc[2], acc[3]);
    }
    __syncthreads();

    // ---- MFMA 32x64, K=64: wave w: rows (w&1)*16, col-tiles {2*(w>>1), +1}
    const int w = tid >> 6, lane = tid & 63;
    const int rg = w & 1, cg = w >> 1;
    const int rloc = rg * 16 + (lane & 15);
    const int arow = min(node0 + rloc, nN - 1);
    const int kg = lane >> 4;
    bf8 ahi[2], alo[2];
    {
        const float* tp = &tile[rloc * 36 + kg * 8];
        split8(*reinterpret_cast<const float4*>(tp),
               *reinterpret_cast<const float4*>(tp + 4), ahi[0], alo[0]);
    }
    {
        const float* rp = x + (size_t)arow * 32 + kg * 8;
        split8(*reinterpret_cast<const float4*>(rp),
               *reinterpret_cast<const float4*>(rp + 4), ahi[1], alo[1]);
    }
    const bf8* bgl = reinterpret_cast<const bf8*>(wfrag);
#pragma unroll
    for (int cc = 0; cc < 2; ++cc) {
        const int ct = cg * 2 + cc;
        f32x4 acc = {0.f, 0.f, 0.f, 0.f};
#pragma unroll
        for (int kc = 0; kc < 2; ++kc) {
            const bf8 bhi = bgl[((ct * 2 + kc) * 2 + 0) * 64 + lane];
            const bf8 blo = bgl[((ct * 2 + kc) * 2 + 1) * 64 + lane];
            acc = __builtin_amdgcn_mfma_f32_16x16x32_bf16(ahi[kc], bhi, acc, 0, 0, 0);
            acc = __builtin_amdgcn_mfma_f32_16x16x32_bf16(ahi[kc], blo, acc, 0, 0, 0);
            acc = __builtin_amdgcn_mfma_f32_16x16x32_bf16(alo[kc], bhi, acc, 0, 0, 0);
        }
        const int col = ct * 16 + (lane & 15);
        const float bv = b1[col];
#pragma unroll
        for (int r = 0; r < 4; ++r) {
            const int node = node0 + rg * 16 + (lane >> 4) * 4 + r;
            if (node < nN) {
                const float o = fmaxf(acc[r] + bv, 0.f);
                const ushort hi = bf16rn(o);
                h1h[(size_t)node * 64 + col] = hi;
                h1l[(size_t)node * 64 + col] = bf16rn(o - bf16tof(hi));
            }
        }
    }
}

// ---- layer 2 fused (32-node tile): h2(hi/lo) = relu([mean(h1h)|h1]@W2+b2) -
__global__ __launch_bounds__(256) void fused_layer2(
    const ushort* __restrict__ h1h, const ushort* __restrict__ h1l,
    const int* __restrict__ rowptr, const ushort* __restrict__ csr_src,
    const ushort* __restrict__ wfrag, const float* __restrict__ b2,
    ushort* __restrict__ h2h, ushort* __restrict__ h2l, int nN)
{
    __shared__ float tile[32 * 68];          // 8704 B

    const int tid = threadIdx.x;
    const int node0 = blockIdx.x * 32;

    {   // gather mean(h1h): 32 nodes x 8 lanes x 8ch (16B loads), one pass
        const int nl = tid >> 3;
        const int c = tid & 7;
        const int node = node0 + nl;
        float acc[8] = {0.f, 0.f, 0.f, 0.f, 0.f, 0.f, 0.f, 0.f};
        if (node < nN) {
            const int beg = rowptr[node], end = rowptr[node + 1];
            int e = beg;
            for (; e + 7 < end; e += 8) {
                int si[8];
#pragma unroll
                for (int j = 0; j < 8; ++j) si[j] = csr_src[e + j];
                bf8 v[8];
#pragma unroll
                for (int j = 0; j < 8; ++j)
                    v[j] = *reinterpret_cast<const bf8*>(h1h + (size_t)si[j] * 64 + c * 8);
#pragma unroll
                for (int k = 0; k < 8; ++k)
#pragma unroll
                    for (int j = 0; j < 8; ++j) acc[k] += bf16tof((ushort)v[j][k]);
            }
            for (; e < end; ++e) {
                bf8 v = *reinterpret_cast<const bf8*>(h1h + (size_t)csr_src[e] * 64 + c * 8);
#pragma unroll
                for (int k = 0; k < 8; ++k) acc[k] += bf16tof((ushort)v[k]);
            }
            const float sc = 1.0f / (float)max(end - beg, 1);
#pragma unroll
            for (int k = 0; k < 8; ++k) acc[k] *= sc;
        }
        *reinterpret_cast<float4*>(&tile[nl * 68 + c * 8 + 0]) =
            make_float4(acc[0], acc[1], acc[2], acc[3]);
        *reinterpret_cast<float4*>(&tile[nl * 68 + c * 8 + 4]) =
            make_float4(acc[4], acc[5], acc[6], acc[7]);
    }
    __syncthreads();

    // ---- MFMA 32x128, K=128: wave w: rows (w&1)*16, cols (w>>1)*64
    const int w = tid >> 6, lane = tid & 63;
    const int rg = w & 1, cg = w >> 1;
    const int rloc = rg * 16 + (lane & 15);
    const int arow = min(node0 + rloc, nN - 1);
    const int kg = lane >> 4;
    bf8 ahi[4], alo[4];
#pragma unroll
    for (int kc = 0; kc < 2; ++kc) {
        const float* tp = &tile[rloc * 68 + kc * 32 + kg * 8];
        split8(*reinterpret_cast<const float4*>(tp),
               *reinterpret_cast<const float4*>(tp + 4), ahi[kc], alo[kc]);
    }
#pragma unroll
    for (int kc = 2; kc < 4; ++kc) {    // self: hi/lo planes ARE the split
        const size_t off = (size_t)arow * 64 + (kc - 2) * 32 + kg * 8;
        ahi[kc] = *reinterpret_cast<const bf8*>(h1h + off);
        alo[kc] = *reinterpret_cast<const bf8*>(h1l + off);
    }
    const bf8* bgl = reinterpret_cast<const bf8*>(wfrag) + cg * 2048;
#pragma unroll
    for (int ctl = 0; ctl < 4; ++ctl) {
        f32x4 acc = {0.f, 0.f, 0.f, 0.f};
#pragma unroll
        for (int kc = 0; kc < 4; ++kc) {
            const bf8 bhi = bgl[((ctl * 4 + kc) * 2 + 0) * 64 + lane];
            const bf8 blo = bgl[((ctl * 4 + kc) * 2 + 1) * 64 + lane];
            acc = __builtin_amdgcn_mfma_f32_16x16x32_bf16(ahi[kc], bhi, acc, 0, 0, 0);
            acc = __builtin_amdgcn_mfma_f32_16x16x32_bf16(ahi[kc], blo, acc, 0, 0, 0);
            acc = __builtin_amdgcn_mfma_f32_16x16x32_bf16(alo[kc], bhi, acc, 0, 0, 0);
        }
        const int col = cg * 64 + ctl * 16 + (lane & 15);
        const float bv = b2[col];
#pragma unroll
        for (int r = 0; r < 4; ++r) {
            const int node = node0 + rg * 16 + (lane >> 4) * 4 + r;
            if (node < nN) {
                const float o = fmaxf(acc[r] + bv, 0.f);
                const ushort hi = bf16rn(o);
                h2h[(size_t)node * 128 + col] = hi;
                h2l[(size_t)node * 128 + col] = bf16rn(o - bf16tof(hi));
            }
        }
    }
}

// ---- layer 3 merged dual GEMM: t3h = bf16(h2@w3l); r3h = bf16(h2@w3r+b3) --
__global__ __launch_bounds__(256) void mfma_dual(
    const ushort* __restrict__ h2h, const ushort* __restrict__ h2l,
    const ushort* __restrict__ wfrag, const float* __restrict__ b3,
    ushort* __restrict__ t3h, ushort* __restrict__ r3h, int nN)
{
    const int tid = threadIdx.x;
    const int w = tid >> 6, lane = tid & 63;
    const int node0 = blockIdx.x * 64;
    const int arow = min(node0 + w * 16 + (lane & 15), nN - 1);
    const int kg = lane >> 4;

    bf8 ahi[4], alo[4];
#pragma unroll
    for (int kc = 0; kc < 4; ++kc) {
        const size_t off = (size_t)arow * 128 + kc * 32 + kg * 8;
        ahi[kc] = *reinterpret_cast<const bf8*>(h2h + off);
        alo[kc] = *reinterpret_cast<const bf8*>(h2l + off);
    }
#pragma unroll
    for (int sel = 0; sel < 2; ++sel) {
        const bf8* bgl = reinterpret_cast<const bf8*>(wfrag) + sel * 2048;
#pragma unroll
        for (int ct = 0; ct < 4; ++ct) {
            f32x4 acc = {0.f, 0.f, 0.f, 0.f};
#pragma unroll
            for (int kc = 0; kc < 4; ++kc) {
                const bf8 bhi = bgl[((ct * 4 + kc) * 2 + 0) * 64 + lane];
                const bf8 blo = bgl[((ct * 4 + kc) * 2 + 1) * 64 + lane];
                acc = __builtin_amdgcn_mfma_f32_16x16x32_bf16(ahi[kc], bhi, acc, 0, 0, 0);
                acc = __builtin_amdgcn_mfma_f32_16x16x32_bf16(ahi[kc], blo, acc, 0, 0, 0);
                acc = __builtin_amdgcn_mfma_f32_16x16x32_bf16(alo[kc], bhi, acc, 0, 0, 0);
            }
            const int col = ct * 16 + (lane & 15);
#pragma unroll
            for (int r = 0; r < 4; ++r) {
                const int node = node0 + w * 16 + (lane >> 4) * 4 + r;
                if (node < nN) {
                    if (sel) r3h[(size_t)node * 64 + col] = bf16rn(acc[r] + b3[col]);
                    else     t3h[(size_t)node * 64 + col] = bf16rn(acc[r]);
                }
            }
        }
    }
}

// ---- final: out = r3h + mean(t3h) -----------------------------------------
__global__ __launch_bounds__(256) void final_gather(
    const ushort* __restrict__ t3h, const int* __restrict__ rowptr,
    const ushort* __restrict__ csr_src, const ushort* __restrict__ r3h,
    float* __restrict__ dout, int nN)
{
    const int tid = threadIdx.x;
    const int node = blockIdx.x * 32 + (tid >> 3);
    const int c = tid & 7;
    if (node >= nN) return;
    const int beg = rowptr[node], end = rowptr[node + 1];
    float acc[8] = {0.f, 0.f, 0.f, 0.f, 0.f, 0.f, 0.f, 0.f};
    int e = beg;
    for (; e + 7 < end; e += 8) {
        int si[8];
#pragma unroll
        for (int j = 0; j < 8; ++j) si[j] = csr_src[e + j];
        bf8 v[8];
#pragma unroll
        for (int j = 0; j < 8; ++j)
            v[j] = *reinterpret_cast<const bf8*>(t3h + (size_t)si[j] * 64 + c * 8);
#pragma unroll
        for (int k = 0; k < 8; ++k)
#pragma unroll
            for (int j = 0; j < 8; ++j) acc[k] += bf16tof((ushort)v[j][k]);
    }
    for (; e < end; ++e) {
        bf8 v = *reinterpret_cast<const bf8*>(t3h + (size_t)csr_src[e] * 64 + c * 8);
#pragma unroll
        for (int k = 0; k < 8; ++k) acc[k] += bf16tof((ushort)v[k]);
    }
    const float sc = 1.0f / (float)max(end - beg, 1);
    const bf8 a = *reinterpret_cast<const bf8*>(r3h + (size_t)node * 64 + c * 8);
    float4 o0, o1;
    o0.x = fmaf(acc[0], sc, bf16tof((ushort)a[0]));
    o0.y = fmaf(acc[1], sc, bf16tof((ushort)a[1]));
    o0.z = fmaf(acc[2], sc, bf16tof((ushort)a[2]));
    o0.w = fmaf(acc[3], sc, bf16tof((ushort)a[3]));
    o1.x = fmaf(acc[4], sc, bf16tof((ushort)a[4]));
    o1.y = fmaf(acc[5], sc, bf16tof((ushort)a[5]));
    o1.z = fmaf(acc[6], sc, bf16tof((ushort)a[6]));
    o1.w = fmaf(acc[7], sc, bf16tof((ushort)a[7]));
    reinterpret_cast<float4*>(dout)[(size_t)node * 16 + c * 2 + 0] = o0;
    reinterpret_cast<float4*>(dout)[(size_t)node * 16 + c * 2 + 1] = o1;
}

extern "C" void kernel_launch(void* const* d_in, const int* in_sizes, int n_in,
                              void* d_out, int out_size, void* d_ws, size_t ws_size,
                              hipStream_t stream) {
    const float* x   = (const float*)d_in[0];
    const int*   ei  = (const int*)d_in[1];
    const float* w1l = (const float*)d_in[2];
    const float* b1  = (const float*)d_in[3];
    const float* w1r = (const float*)d_in[4];
    const float* w2l = (const float*)d_in[5];
    const float* b2  = (const float*)d_in[6];
    const float* w2r = (const float*)d_in[7];
    const float* w3l = (const float*)d_in[8];
    const float* b3  = (const float*)d_in[9];
    const float* w3r = (const float*)d_in[10];

    const int nN = in_sizes[0] / 32;   // 50000 (< 65536: ushort indices valid)
    const int nE = in_sizes[1] / 2;    // 640000
    const int* src = ei;
    const int* dst = ei + nE;
    const int nB = (nN + 1023) / 1024; // 49 scan blocks (<= 64)
    const int nCntZero = (nN + 63) & ~63;

    char* ws = (char*)d_ws;
    size_t o = 0;
    auto alloc = [&](size_t nbytes) {
        char* p = ws + o;
        o += (nbytes + 255) & ~(size_t)255;
        return p;
    };
    int*    cnt      = (int*)alloc((size_t)nCntZero * sizeof(int));
    ushort* pos      = (ushort*)alloc((size_t)nE * sizeof(ushort));
    int*    partials = (int*)alloc(64 * sizeof(int));
    int*    rowptr   = (int*)alloc(((size_t)nN + 1) * sizeof(int));
    ushort* csr_src  = (ushort*)alloc((size_t)nE * sizeof(ushort));
    ushort* wprep    = (ushort*)alloc((size_t)9216 * 8 * sizeof(ushort)); // 144KB
    ushort* xh       = (ushort*)alloc((size_t)nN * 32 * sizeof(ushort));
    ushort* h1h      = (ushort*)alloc((size_t)nN * 64 * sizeof(ushort));
    ushort* h1l      = (ushort*)alloc((size_t)nN * 64 * sizeof(ushort));
    ushort* h2h      = (ushort*)alloc((size_t)nN * 128 * sizeof(ushort));
    ushort* h2l      = (ushort*)alloc((size_t)nN * 128 * sizeof(ushort));
    ushort* t3h      = (ushort*)alloc((size_t)nN * 64 * sizeof(ushort));
    ushort* r3h      = (ushort*)alloc((size_t)nN * 64 * sizeof(ushort));

    // ---- prep (weights + zero + x->bf16)
    prep_kernel<<<784, 256, 0, stream>>>(x, w1l, w1r, w2l, w2r, w3l, w3r,
                                         wprep, cnt, xh, nN, nCntZero);
    // ---- CSR build
    count_kernel<<<(nE / 4 + 255) / 256, 256, 0, stream>>>(dst, cnt, pos, nE);
    scan_blocks<<<nB, 256, 0, stream>>>(cnt, rowptr, partials, nN);
    scan_add<<<nB, 256, 0, stream>>>(rowptr, partials, nN, nE);
    fill_kernel<<<(nE / 4 + 255) / 256, 256, 0, stream>>>(src, dst, pos, rowptr, csr_src, nE);

    const int xblk32 = (nN + 31) / 32;   // 1563
    const int xblk64 = (nN + 63) / 64;   // 782

    // ---- layer 1 fused (32-node tiles)
    fused_layer1<<<xblk32, 256, 0, stream>>>(x, xh, rowptr, csr_src, wprep, b1, h1h, h1l, nN);
    // ---- layer 2 fused (32-node tiles)
    fused_layer2<<<xblk32, 256, 0, stream>>>(h1h, h1l, rowptr, csr_src,
                                             wprep + (size_t)1024 * 8, b2, h2h, h2l, nN);
    // ---- layer 3 merged dual GEMM
    mfma_dual<<<xblk64, 256, 0, stream>>>(h2h, h2l, wprep + (size_t)5120 * 8, b3, t3h, r3h, nN);
    // ---- final gather
    final_gather<<<(nN + 31) / 32, 256, 0, stream>>>(t3h, rowptr, csr_src, r3h, (float*)d_out, nN);
}

// Round 13
// 139.489 us; speedup vs baseline: 1.0157x; 1.0157x over previous
//
#include <hip/hip_runtime.h>

// ---------------------------------------------------------------------------
// GraphSAGE 3-layer encoder. N=50000, E=640000, ch 32 -> 64 -> 128 -> 64.
// R13: (a) h2 lo-plane dropped (dual GEMM A = plain bf16 h2; weights stay
// hi/lo) -> -25.6MB traffic + 1/3 fewer dual MFMAs; (b) prep+count merged
// into one kernel (cnt zeroed via 200KB hipMemsetAsync) -> one gap removed.
// Gathers proven byte-bound (R9 -40us on byte-halving; R12 occupancy null).
// GEMM math: split-bf16 MFMA (hi*hi + hi*lo + lo*hi, fp32 acc).
// ---------------------------------------------------------------------------

typedef short bf8 __attribute__((ext_vector_type(8)));   // 8 bf16 in 4 VGPR
typedef short bf4 __attribute__((ext_vector_type(4)));   // 4 bf16 in 2 VGPR
typedef float f32x4 __attribute__((ext_vector_type(4)));

__device__ inline ushort bf16rn(float f) {               // round-to-nearest-even
    unsigned u = __float_as_uint(f);
    return (ushort)((u + 0x7FFFu + ((u >> 16) & 1u)) >> 16);
}
__device__ inline float bf16tof(ushort h) {
    return __uint_as_float(((unsigned)h) << 16);
}
__device__ inline void split8(const float4 pa, const float4 pb, bf8& hi, bf8& lo) {
    const float v[8] = {pa.x, pa.y, pa.z, pa.w, pb.x, pb.y, pb.z, pb.w};
#pragma unroll
    for (int j = 0; j < 8; ++j) {
        const ushort h = bf16rn(v[j]);
        hi[j] = (short)h;
        lo[j] = (short)bf16rn(v[j] - bf16tof(h));
    }
}

// ---- merged prep (weights hi/lo frags + x->bf16) + count (degree + slot) --
__global__ __launch_bounds__(256) void prep_count_kernel(
    const float* __restrict__ x,
    const float* __restrict__ w1l, const float* __restrict__ w1r,
    const float* __restrict__ w2l, const float* __restrict__ w2r,
    const float* __restrict__ w3l, const float* __restrict__ w3r,
    ushort* __restrict__ wprep, ushort* __restrict__ xh,
    const int* __restrict__ dst, int* __restrict__ cnt,
    ushort* __restrict__ pos, int nN, int nE)
{
    const int g = blockIdx.x * 256 + threadIdx.x;
    const int n = gridDim.x * 256;
    // -- weight fragments
    for (int f = g; f < 9216; f += n) {
        int base, KCs, oc0, d0, wstride;
        const float *wa, *wb;
        if (f < 1024)      { base = 0;    KCs = 2; oc0 = 0;  wa = w1l; wb = w1r; d0 = 32;  wstride = 64;  }
        else if (f < 3072) { base = 1024; KCs = 4; oc0 = 0;  wa = w2l; wb = w2r; d0 = 64;  wstride = 128; }
        else if (f < 5120) { base = 3072; KCs = 4; oc0 = 64; wa = w2l; wb = w2r; d0 = 64;  wstride = 128; }
        else if (f < 7168) { base = 5120; KCs = 4; oc0 = 0;  wa = w3l; wb = w3l; d0 = 128; wstride = 64;  }
        else               { base = 7168; KCs = 4; oc0 = 0;  wa = w3r; wb = w3r; d0 = 128; wstride = 64;  }
        const int local = f - base;
        const int lane = local & 63;
        const int s = (local >> 6) & 1;
        const int kcct = local >> 7;
        const int kc = kcct % KCs;
        const int ct = kcct / KCs;
        const int col = oc0 + ct * 16 + (lane & 15);
        const int k0 = kc * 32 + (lane >> 4) * 8;
        ushort h8[8];
#pragma unroll
        for (int j = 0; j < 8; ++j) {
            const int k = k0 + j;
            const float* wr = (k < d0) ? (wa + (size_t)k * wstride)
                                       : (wb + (size_t)(k - d0) * wstride);
            const float v = wr[col];
            const ushort h = bf16rn(v);
            h8[j] = (s == 0) ? h : bf16rn(v - bf16tof(h));
        }
        *reinterpret_cast<int4*>(wprep + (size_t)f * 8) = *reinterpret_cast<const int4*>(h8);
    }
    // -- x -> bf16
    const int nxv = nN * 4;                       // 8-element groups of x
    for (int i = g; i < nxv; i += n) {
        const float4 a = reinterpret_cast<const float4*>(x)[i * 2 + 0];
        const float4 b = reinterpret_cast<const float4*>(x)[i * 2 + 1];
        const float v[8] = {a.x, a.y, a.z, a.w, b.x, b.y, b.z, b.w};
        bf8 h;
#pragma unroll
        for (int j = 0; j < 8; ++j) h[j] = (short)bf16rn(v[j]);
        reinterpret_cast<bf8*>(xh)[i] = h;
    }
    // -- count: degree + per-edge slot (cnt pre-zeroed by memset)
    const int n4 = nE >> 2;
    for (int i = g; i < n4; i += n) {
        int4 d = reinterpret_cast<const int4*>(dst)[i];
        ushort4 p;
        p.x = (ushort)atomicAdd(&cnt[d.x], 1);
        p.y = (ushort)atomicAdd(&cnt[d.y], 1);
        p.z = (ushort)atomicAdd(&cnt[d.z], 1);
        p.w = (ushort)atomicAdd(&cnt[d.w], 1);
        reinterpret_cast<ushort4*>(pos)[i] = p;
    }
    for (int e = (nE & ~3) + g; e < nE; e += n)
        pos[e] = (ushort)atomicAdd(&cnt[dst[e]], 1);
}

__global__ __launch_bounds__(256) void scan_blocks(const int* __restrict__ cnt,
                                                   int* __restrict__ rowptr,
                                                   int* __restrict__ partials, int nN) {
    __shared__ int wsum[4];
    const int t = threadIdx.x;
    const int lane = t & 63, wid = t >> 6;
    const int base = blockIdx.x * 1024 + t * 4;

    int4 v = make_int4(0, 0, 0, 0);
    if (base + 3 < nN) {
        v = *reinterpret_cast<const int4*>(cnt + base);
    } else {
        if (base + 0 < nN) v.x = cnt[base + 0];
        if (base + 1 < nN) v.y = cnt[base + 1];
        if (base + 2 < nN) v.z = cnt[base + 2];
        if (base + 3 < nN) v.w = cnt[base + 3];
    }
    const int s = v.x + v.y + v.z + v.w;

    int inc = s;
#pragma unroll
    for (int d = 1; d < 64; d <<= 1) {
        int u = __shfl_up(inc, d);
        if (lane >= d) inc += u;
    }
    if (lane == 63) wsum[wid] = inc;
    __syncthreads();
    int woff = 0;
#pragma unroll
    for (int w = 0; w < 4; ++w) woff += (w < wid) ? wsum[w] : 0;

    const int excl = woff + inc - s;
    int4 o;
    o.x = excl; o.y = excl + v.x; o.z = excl + v.x + v.y; o.w = excl + v.x + v.y + v.z;
    if (base + 3 < nN) {
        *reinterpret_cast<int4*>(rowptr + base) = o;
    } else {
        if (base + 0 < nN) rowptr[base + 0] = o.x;
        if (base + 1 < nN) rowptr[base + 1] = o.y;
        if (base + 2 < nN) rowptr[base + 2] = o.z;
        if (base + 3 < nN) rowptr[base + 3] = o.w;
    }
    if (t == 255) partials[blockIdx.x] = woff + inc;
}

__global__ __launch_bounds__(256) void scan_add(int* __restrict__ rowptr,
                                                const int* __restrict__ partials,
                                                int nN, int nE) {
    __shared__ int soff;
    const int t = threadIdx.x;
    if (t < 64) {
        int v = (t < blockIdx.x) ? partials[t] : 0;   // grid <= 64 blocks
#pragma unroll
        for (int d = 32; d >= 1; d >>= 1) v += __shfl_xor(v, d);
        if (t == 0) soff = v;
    }
    __syncthreads();
    const int off = soff;
    const int base = blockIdx.x * 1024 + t * 4;
    if (base + 3 < nN) {
        int4 v = *reinterpret_cast<int4*>(rowptr + base);
        v.x += off; v.y += off; v.z += off; v.w += off;
        *reinterpret_cast<int4*>(rowptr + base) = v;
    } else {
        if (base + 0 < nN) rowptr[base + 0] += off;
        if (base + 1 < nN) rowptr[base + 1] += off;
        if (base + 2 < nN) rowptr[base + 2] += off;
        if (base + 3 < nN) rowptr[base + 3] += off;
    }
    if (blockIdx.x == 0 && t == 0) rowptr[nN] = nE;
}

// ---- fill: pure permutation write (no atomics), ushort csr ----------------
__global__ __launch_bounds__(256) void fill_kernel(const int* __restrict__ src,
                                                   const int* __restrict__ dst,
                                                   const ushort* __restrict__ pos,
                                                   const int* __restrict__ rowptr,
                                                   ushort* __restrict__ csr_src, int nE) {
    int i = blockIdx.x * blockDim.x + threadIdx.x;
    int e0 = i * 4;
    if (e0 + 3 < nE) {
        int4 s4 = *reinterpret_cast<const int4*>(src + e0);
        int4 d4 = *reinterpret_cast<const int4*>(dst + e0);
        ushort4 p4 = *reinterpret_cast<const ushort4*>(pos + e0);
        csr_src[rowptr[d4.x] + p4.x] = (ushort)s4.x;
        csr_src[rowptr[d4.y] + p4.y] = (ushort)s4.y;
        csr_src[rowptr[d4.z] + p4.z] = (ushort)s4.z;
        csr_src[rowptr[d4.w] + p4.w] = (ushort)s4.w;
    } else {
        for (int e = e0; e < nE; ++e)
            csr_src[rowptr[dst[e]] + pos[e]] = (ushort)src[e];
    }
}

// ---- layer 1 fused (32-node tile): h1(hi/lo) = relu([mean(xh)|x]@W1 + b1) -
__global__ __launch_bounds__(256) void fused_layer1(
    const float* __restrict__ x, const ushort* __restrict__ xh,
    const int* __restrict__ rowptr, const ushort* __restrict__ csr_src,
    const ushort* __restrict__ wfrag, const float* __restrict__ b1,
    ushort* __restrict__ h1h, ushort* __restrict__ h1l, int nN)
{
    __shared__ float tile[32 * 36];          // 4608 B

    const int tid = threadIdx.x;
    const int node0 = blockIdx.x * 32;

    {   // gather mean(xh): 32 nodes x 8 lanes x 4ch (8B loads)
        const int nl = tid >> 3;
        const int c = tid & 7;
        const int node = node0 + nl;
        float acc[4] = {0.f, 0.f, 0.f, 0.f};
        if (node < nN) {
            const int beg = rowptr[node], end = rowptr[node + 1];
            int e = beg;
            for (; e + 7 < end; e += 8) {
                int si[8];
#pragma unroll
                for (int j = 0; j < 8; ++j) si[j] = csr_src[e + j];
                bf4 v[8];
#pragma unroll
                for (int j = 0; j < 8; ++j)
                    v[j] = *reinterpret_cast<const bf4*>(xh + (size_t)si[j] * 32 + c * 4);
#pragma unroll
                for (int k = 0; k < 4; ++k)
#pragma unroll
                    for (int j = 0; j < 8; ++j) acc[k] += bf16tof((ushort)v[j][k]);
            }
            for (; e < end; ++e) {
                bf4 v = *reinterpret_cast<const bf4*>(xh + (size_t)csr_src[e] * 32 + c * 4);
#pragma unroll
                for (int k = 0; k < 4; ++k) acc[k] += bf16tof((ushort)v[k]);
            }
            const float sc = 1.0f / (float)max(end - beg, 1);
#pragma unroll
            for (int k = 0; k < 4; ++k) acc[k] *= sc;
        }
        *reinterpret_cast<float4*>(&tile[nl * 36 + c * 4]) =
            make_float4(acc[0], acc[1], acc[2], acc[3]);
    }
    __syncthreads();

    // ---- MFMA 32x64, K=64: wave w: rows (w&1)*16, col-tiles {2*(w>>1), +1}
    const int w = tid >> 6, lane = tid & 63;
    const int rg = w & 1, cg = w >> 1;
    const int rloc = rg * 16 + (lane & 15);
    const int arow = min(node0 + rloc, nN - 1);
    const int kg = lane >> 4;
    bf8 ahi[2], alo[2];
    {
        const float* tp = &tile[rloc * 36 + kg * 8];
        split8(*reinterpret_cast<const float4*>(tp),
               *reinterpret_cast<const float4*>(tp + 4), ahi[0], alo[0]);
    }
    {
        const float* rp = x + (size_t)arow * 32 + kg * 8;
        split8(*reinterpret_cast<const float4*>(rp),
               *reinterpret_cast<const float4*>(rp + 4), ahi[1], alo[1]);
    }
    const bf8* bgl = reinterpret_cast<const bf8*>(wfrag);
#pragma unroll
    for (int cc = 0; cc < 2; ++cc) {
        const int ct = cg * 2 + cc;
        f32x4 acc = {0.f, 0.f, 0.f, 0.f};
#pragma unroll
        for (int kc = 0; kc < 2; ++kc) {
            const bf8 bhi = bgl[((ct * 2 + kc) * 2 + 0) * 64 + lane];
            const bf8 blo = bgl[((ct * 2 + kc) * 2 + 1) * 64 + lane];
            acc = __builtin_amdgcn_mfma_f32_16x16x32_bf16(ahi[kc], bhi, acc, 0, 0, 0);
            acc = __builtin_amdgcn_mfma_f32_16x16x32_bf16(ahi[kc], blo, acc, 0, 0, 0);
            acc = __builtin_amdgcn_mfma_f32_16x16x32_bf16(alo[kc], bhi, acc, 0, 0, 0);
        }
        const int col = ct * 16 + (lane & 15);
        const float bv = b1[col];
#pragma unroll
        for (int r = 0; r < 4; ++r) {
            const int node = node0 + rg * 16 + (lane >> 4) * 4 + r;
            if (node < nN) {
                const float o = fmaxf(acc[r] + bv, 0.f);
                const ushort hi = bf16rn(o);
                h1h[(size_t)node * 64 + col] = hi;
                h1l[(size_t)node * 64 + col] = bf16rn(o - bf16tof(hi));
            }
        }
    }
}

// ---- layer 2 fused (32-node tile): h2h = bf16(relu([mean(h1h)|h1]@W2+b2)) -
__global__ __launch_bounds__(256) void fused_layer2(
    const ushort* __restrict__ h1h, const ushort* __restrict__ h1l,
    const int* __restrict__ rowptr, const ushort* __restrict__ csr_src,
    const ushort* __restrict__ wfrag, const float* __restrict__ b2,
    ushort* __restrict__ h2h, int nN)
{
    __shared__ float tile[32 * 68];          // 8704 B

    const int tid = threadIdx.x;
    const int node0 = blockIdx.x * 32;

    {   // gather mean(h1h): 32 nodes x 8 lanes x 8ch (16B loads)
        const int nl = tid >> 3;
        const int c = tid & 7;
        const int node = node0 + nl;
        float acc[8] = {0.f, 0.f, 0.f, 0.f, 0.f, 0.f, 0.f, 0.f};
        if (node < nN) {
            const int beg = rowptr[node], end = rowptr[node + 1];
            int e = beg;
            for (; e + 7 < end; e += 8) {
                int si[8];
#pragma unroll
                for (int j = 0; j < 8; ++j) si[j] = csr_src[e + j];
                bf8 v[8];
#pragma unroll
                for (int j = 0; j < 8; ++j)
                    v[j] = *reinterpret_cast<const bf8*>(h1h + (size_t)si[j] * 64 + c * 8);
#pragma unroll
                for (int k = 0; k < 8; ++k)
#pragma unroll
                    for (int j = 0; j < 8; ++j) acc[k] += bf16tof((ushort)v[j][k]);
            }
            for (; e < end; ++e) {
                bf8 v = *reinterpret_cast<const bf8*>(h1h + (size_t)csr_src[e] * 64 + c * 8);
#pragma unroll
                for (int k = 0; k < 8; ++k) acc[k] += bf16tof((ushort)v[k]);
            }
            const float sc = 1.0f / (float)max(end - beg, 1);
#pragma unroll
            for (int k = 0; k < 8; ++k) acc[k] *= sc;
        }
        *reinterpret_cast<float4*>(&tile[nl * 68 + c * 8 + 0]) =
            make_float4(acc[0], acc[1], acc[2], acc[3]);
        *reinterpret_cast<float4*>(&tile[nl * 68 + c * 8 + 4]) =
            make_float4(acc[4], acc[5], acc[6], acc[7]);
    }
    __syncthreads();

    // ---- MFMA 32x128, K=128: wave w: rows (w&1)*16, cols (w>>1)*64
    const int w = tid >> 6, lane = tid & 63;
    const int rg = w & 1, cg = w >> 1;
    const int rloc = rg * 16 + (lane & 15);
    const int arow = min(node0 + rloc, nN - 1);
    const int kg = lane >> 4;
    bf8 ahi[4], alo[4];
#pragma unroll
    for (int kc = 0; kc < 2; ++kc) {
        const float* tp = &tile[rloc * 68 + kc * 32 + kg * 8];
        split8(*reinterpret_cast<const float4*>(tp),
               *reinterpret_cast<const float4*>(tp + 4), ahi[kc], alo[kc]);
    }
#pragma unroll
    for (int kc = 2; kc < 4; ++kc) {    // self: hi/lo planes ARE the split
        const size_t off = (size_t)arow * 64 + (kc - 2) * 32 + kg * 8;
        ahi[kc] = *reinterpret_cast<const bf8*>(h1h + off);
        alo[kc] = *reinterpret_cast<const bf8*>(h1l + off);
    }
    const bf8* bgl = reinterpret_cast<const bf8*>(wfrag) + cg * 2048;
#pragma unroll
    for (int ctl = 0; ctl < 4; ++ctl) {
        f32x4 acc = {0.f, 0.f, 0.f, 0.f};
#pragma unroll
        for (int kc = 0; kc < 4; ++kc) {
            const bf8 bhi = bgl[((ctl * 4 + kc) * 2 + 0) * 64 + lane];
            const bf8 blo = bgl[((ctl * 4 + kc) * 2 + 1) * 64 + lane];
            acc = __builtin_amdgcn_mfma_f32_16x16x32_bf16(ahi[kc], bhi, acc, 0, 0, 0);
            acc = __builtin_amdgcn_mfma_f32_16x16x32_bf16(ahi[kc], blo, acc, 0, 0, 0);
            acc = __builtin_amdgcn_mfma_f32_16x16x32_bf16(alo[kc], bhi, acc, 0, 0, 0);
        }
        const int col = cg * 64 + ctl * 16 + (lane & 15);
        const float bv = b2[col];
#pragma unroll
        for (int r = 0; r < 4; ++r) {
            const int node = node0 + rg * 16 + (lane >> 4) * 4 + r;
            if (node < nN)
                h2h[(size_t)node * 128 + col] = bf16rn(fmaxf(acc[r] + bv, 0.f));
        }
    }
}

// ---- layer 3 merged dual GEMM (A = bf16 h2h): t3h = h2@w3l; r3h = h2@w3r+b3
__global__ __launch_bounds__(256) void mfma_dual(
    const ushort* __restrict__ h2h, const ushort* __restrict__ wfrag,
    const float* __restrict__ b3, ushort* __restrict__ t3h,
    ushort* __restrict__ r3h, int nN)
{
    const int tid = threadIdx.x;
    const int w = tid >> 6, lane = tid & 63;
    const int node0 = blockIdx.x * 64;
    const int arow = min(node0 + w * 16 + (lane & 15), nN - 1);
    const int kg = lane >> 4;

    bf8 ahi[4];
#pragma unroll
    for (int kc = 0; kc < 4; ++kc)
        ahi[kc] = *reinterpret_cast<const bf8*>(h2h + (size_t)arow * 128 + kc * 32 + kg * 8);

#pragma unroll
    for (int sel = 0; sel < 2; ++sel) {
        const bf8* bgl = reinterpret_cast<const bf8*>(wfrag) + sel * 2048;
#pragma unroll
        for (int ct = 0; ct < 4; ++ct) {
            f32x4 acc = {0.f, 0.f, 0.f, 0.f};
#pragma unroll
            for (int kc = 0; kc < 4; ++kc) {
                const bf8 bhi = bgl[((ct * 4 + kc) * 2 + 0) * 64 + lane];
                const bf8 blo = bgl[((ct * 4 + kc) * 2 + 1) * 64 + lane];
                acc = __builtin_amdgcn_mfma_f32_16x16x32_bf16(ahi[kc], bhi, acc, 0, 0, 0);
                acc = __builtin_amdgcn_mfma_f32_16x16x32_bf16(ahi[kc], blo, acc, 0, 0, 0);
            }
            const int col = ct * 16 + (lane & 15);
#pragma unroll
            for (int r = 0; r < 4; ++r) {
                const int node = node0 + w * 16 + (lane >> 4) * 4 + r;
                if (node < nN) {
                    if (sel) r3h[(size_t)node * 64 + col] = bf16rn(acc[r] + b3[col]);
                    else     t3h[(size_t)node * 64 + col] = bf16rn(acc[r]);
                }
            }
        }
    }
}

// ---- final: out = r3h + mean(t3h) -----------------------------------------
__global__ __launch_bounds__(256) void final_gather(
    const ushort* __restrict__ t3h, const int* __restrict__ rowptr,
    const ushort* __restrict__ csr_src, const ushort* __restrict__ r3h,
    float* __restrict__ dout, int nN)
{
    const int tid = threadIdx.x;
    const int node = blockIdx.x * 32 + (tid >> 3);
    const int c = tid & 7;
    if (node >= nN) return;
    const int beg = rowptr[node], end = rowptr[node + 1];
    float acc[8] = {0.f, 0.f, 0.f, 0.f, 0.f, 0.f, 0.f, 0.f};
    int e = beg;
    for (; e + 7 < end; e += 8) {
        int si[8];
#pragma unroll
        for (int j = 0; j < 8; ++j) si[j] = csr_src[e + j];
        bf8 v[8];
#pragma unroll
        for (int j = 0; j < 8; ++j)
            v[j] = *reinterpret_cast<const bf8*>(t3h + (size_t)si[j] * 64 + c * 8);
#pragma unroll
        for (int k = 0; k < 8; ++k)
#pragma unroll
            for (int j = 0; j < 8; ++j) acc[k] += bf16tof((ushort)v[j][k]);
    }
    for (; e < end; ++e) {
        bf8 v = *reinterpret_cast<const bf8*>(t3h + (size_t)csr_src[e] * 64 + c * 8);
#pragma unroll
        for (int k = 0; k < 8; ++k) acc[k] += bf16tof((ushort)v[k]);
    }
    const float sc = 1.0f / (float)max(end - beg, 1);
    const bf8 a = *reinterpret_cast<const bf8*>(r3h + (size_t)node * 64 + c * 8);
    float4 o0, o1;
    o0.x = fmaf(acc[0], sc, bf16tof((ushort)a[0]));
    o0.y = fmaf(acc[1], sc, bf16tof((ushort)a[1]));
    o0.z = fmaf(acc[2], sc, bf16tof((ushort)a[2]));
    o0.w = fmaf(acc[3], sc, bf16tof((ushort)a[3]));
    o1.x = fmaf(acc[4], sc, bf16tof((ushort)a[4]));
    o1.y = fmaf(acc[5], sc, bf16tof((ushort)a[5]));
    o1.z = fmaf(acc[6], sc, bf16tof((ushort)a[6]));
    o1.w = fmaf(acc[7], sc, bf16tof((ushort)a[7]));
    reinterpret_cast<float4*>(dout)[(size_t)node * 16 + c * 2 + 0] = o0;
    reinterpret_cast<float4*>(dout)[(size_t)node * 16 + c * 2 + 1] = o1;
}

extern "C" void kernel_launch(void* const* d_in, const int* in_sizes, int n_in,
                              void* d_out, int out_size, void* d_ws, size_t ws_size,
                              hipStream_t stream) {
    const float* x   = (const float*)d_in[0];
    const int*   ei  = (const int*)d_in[1];
    const float* w1l = (const float*)d_in[2];
    const float* b1  = (const float*)d_in[3];
    const float* w1r = (const float*)d_in[4];
    const float* w2l = (const float*)d_in[5];
    const float* b2  = (const float*)d_in[6];
    const float* w2r = (const float*)d_in[7];
    const float* w3l = (const float*)d_in[8];
    const float* b3  = (const float*)d_in[9];
    const float* w3r = (const float*)d_in[10];

    const int nN = in_sizes[0] / 32;   // 50000 (< 65536: ushort indices valid)
    const int nE = in_sizes[1] / 2;    // 640000
    const int* src = ei;
    const int* dst = ei + nE;
    const int nB = (nN + 1023) / 1024; // 49 scan blocks (<= 64)
    const int nCntZero = (nN + 63) & ~63;

    char* ws = (char*)d_ws;
    size_t o = 0;
    auto alloc = [&](size_t nbytes) {
        char* p = ws + o;
        o += (nbytes + 255) & ~(size_t)255;
        return p;
    };
    int*    cnt      = (int*)alloc((size_t)nCntZero * sizeof(int));
    ushort* pos      = (ushort*)alloc((size_t)nE * sizeof(ushort));
    int*    partials = (int*)alloc(64 * sizeof(int));
    int*    rowptr   = (int*)alloc(((size_t)nN + 1) * sizeof(int));
    ushort* csr_src  = (ushort*)alloc((size_t)nE * sizeof(ushort));
    ushort* wprep    = (ushort*)alloc((size_t)9216 * 8 * sizeof(ushort)); // 144KB
    ushort* xh       = (ushort*)alloc((size_t)nN * 32 * sizeof(ushort));
    ushort* h1h      = (ushort*)alloc((size_t)nN * 64 * sizeof(ushort));
    ushort* h1l      = (ushort*)alloc((size_t)nN * 64 * sizeof(ushort));
    ushort* h2h      = (ushort*)alloc((size_t)nN * 128 * sizeof(ushort));
    ushort* t3h      = (ushort*)alloc((size_t)nN * 64 * sizeof(ushort));
    ushort* r3h      = (ushort*)alloc((size_t)nN * 64 * sizeof(ushort));

    // ---- zero cnt (200KB, ~0 us) then merged prep+count
    hipMemsetAsync(cnt, 0, (size_t)nCntZero * sizeof(int), stream);
    prep_count_kernel<<<784, 256, 0, stream>>>(x, w1l, w1r, w2l, w2r, w3l, w3r,
                                               wprep, xh, dst, cnt, pos, nN, nE);
    // ---- CSR build
    scan_blocks<<<nB, 256, 0, stream>>>(cnt, rowptr, partials, nN);
    scan_add<<<nB, 256, 0, stream>>>(rowptr, partials, nN, nE);
    fill_kernel<<<(nE / 4 + 255) / 256, 256, 0, stream>>>(src, dst, pos, rowptr, csr_src, nE);

    const int xblk32 = (nN + 31) / 32;   // 1563
    const int xblk64 = (nN + 63) / 64;   // 782

    // ---- layer 1 fused (32-node tiles)
    fused_layer1<<<xblk32, 256, 0, stream>>>(x, xh, rowptr, csr_src, wprep, b1, h1h, h1l, nN);
    // ---- layer 2 fused (32-node tiles; h2 stored bf16)
    fused_layer2<<<xblk32, 256, 0, stream>>>(h1h, h1l, rowptr, csr_src,
                                             wprep + (size_t)1024 * 8, b2, h2h, nN);
    // ---- layer 3 merged dual GEMM (A = bf16 h2)
    mfma_dual<<<xblk64, 256, 0, stream>>>(h2h, wprep + (size_t)5120 * 8, b3, t3h, r3h, nN);
    // ---- final gather
    final_gather<<<(nN + 31) / 32, 256, 0, stream>>>(t3h, rowptr, csr_src, r3h, (float*)d_out, nN);
}